// Round 6
// baseline (712.193 us; speedup 1.0000x reference)
//
#include <hip/hip_runtime.h>
#include <stdint.h>

#define B_BATCH 8
#define S_SEQ   4096
#define D_DIM   1024
#define H_DIM   2048
#define M_TOK   (B_BATCH * S_SEQ)   // 32768
#define MAXK    64
#define NSPLIT  2                   // H halves; one half per XCD parity

typedef unsigned int u32;
typedef unsigned short u16;
typedef unsigned long long u64;
typedef __attribute__((ext_vector_type(8))) short short8;   // 8 bf16 (4 VGPRs)
typedef __attribute__((ext_vector_type(4))) float f32x4;

#define GLOBAL_AS __attribute__((address_space(1)))
#define LDS_AS    __attribute__((address_space(3)))

// ---------------- JAX threefry2x32 (20 rounds), partitionable mode ----------------

#define TF_ROUND(x0, x1, r) { x0 += x1; x1 = ((x1 << r) | (x1 >> (32 - r))); x1 ^= x0; }

__device__ __forceinline__ void tf2x32(u32 k0, u32 k1, u32 x0, u32 x1, u32& o0, u32& o1) {
  u32 k2 = k0 ^ k1 ^ 0x1BD11BDAu;
  x0 += k0; x1 += k1;
  TF_ROUND(x0, x1, 13) TF_ROUND(x0, x1, 15) TF_ROUND(x0, x1, 26) TF_ROUND(x0, x1, 6)
  x0 += k1; x1 += k2 + 1u;
  TF_ROUND(x0, x1, 17) TF_ROUND(x0, x1, 29) TF_ROUND(x0, x1, 16) TF_ROUND(x0, x1, 24)
  x0 += k2; x1 += k0 + 2u;
  TF_ROUND(x0, x1, 13) TF_ROUND(x0, x1, 15) TF_ROUND(x0, x1, 26) TF_ROUND(x0, x1, 6)
  x0 += k0; x1 += k1 + 3u;
  TF_ROUND(x0, x1, 17) TF_ROUND(x0, x1, 29) TF_ROUND(x0, x1, 16) TF_ROUND(x0, x1, 24)
  x0 += k1; x1 += k2 + 4u;
  TF_ROUND(x0, x1, 13) TF_ROUND(x0, x1, 15) TF_ROUND(x0, x1, 26) TF_ROUND(x0, x1, 6)
  x0 += k2; x1 += k0 + 5u;
  o0 = x0; o1 = x1;
}

__device__ __forceinline__ void jax_subkeys(u32& r1a, u32& r1b, u32& r2a, u32& r2b) {
  tf2x32(0u, 42u, 0u, 0u, r1a, r1b);
  tf2x32(0u, 42u, 0u, 1u, r2a, r2b);
}

__device__ __forceinline__ u32 jax_bits32(u32 ka, u32 kb, u32 i) {
  u32 o0, o1;
  tf2x32(ka, kb, 0u, i, o0, o1);
  return o0 ^ o1;
}

__device__ __forceinline__ float jax_uniform_from_bits(u32 bits) {
  float f = __uint_as_float((bits >> 9) | 0x3f800000u) - 1.0f;
  float r = f + 1e-8f;
  return fmaxf(1e-8f, r);
}

__device__ __forceinline__ float gumbel_from_bits(u32 bits) {
  float u = jax_uniform_from_bits(bits);
  return -logf(-logf(u));
}

__device__ __forceinline__ u32 ordf(float v) {
  u32 b = __float_as_uint(v);
  return (b & 0x80000000u) ? ~b : (b | 0x80000000u);
}

__device__ __forceinline__ u64 shflx64(u64 v, int m) {
  unsigned lo = (unsigned)v, hi = (unsigned)(v >> 32);
  lo = (unsigned)__shfl_xor((int)lo, m);
  hi = (unsigned)__shfl_xor((int)hi, m);
  return ((u64)hi << 32) | lo;
}

// ---------------- bf16 split helpers ----------------

__device__ __forceinline__ u16 f2bf_rn(float x) {
  u32 u = __float_as_uint(x);
  u32 r = u + 0x7fffu + ((u >> 16) & 1u);
  return (u16)(r >> 16);
}

__device__ __forceinline__ void split1(float x, u16& h, u16& lo) {
  h = f2bf_rn(x);
  float hf = __uint_as_float(((u32)h) << 16);
  lo = f2bf_rn(x - hf);
}

// ---------------- fused split pre-pass ----------------
// blocks [0, NA_BLK): grid-stride bf16-split of emb -> Ahi/Alo
// blocks [NA_BLK, NA_BLK+2048): W1 [D][H] -> W1t [H][D] transpose + split

#define NA_BLK 4096

__global__ __launch_bounds__(256) void split_fuse(
    const float* __restrict__ emb, u16* __restrict__ Ahi, u16* __restrict__ Alo,
    const float* __restrict__ W1, u16* __restrict__ Bhi, u16* __restrict__ Blo) {
  if (blockIdx.x < NA_BLK) {
    const size_t total = (size_t)M_TOK * D_DIM / 4;
    for (size_t g = (size_t)blockIdx.x * 256 + threadIdx.x; g < total;
         g += (size_t)NA_BLK * 256) {
      float4 v = ((const float4*)emb)[g];
      u16 h0, h1, h2, h3, l0, l1, l2, l3;
      split1(v.x, h0, l0); split1(v.y, h1, l1); split1(v.z, h2, l2); split1(v.w, h3, l3);
      u64 hv = (u64)h0 | ((u64)h1 << 16) | ((u64)h2 << 32) | ((u64)h3 << 48);
      u64 lv = (u64)l0 | ((u64)l1 << 16) | ((u64)l2 << 32) | ((u64)l3 << 48);
      ((u64*)Ahi)[g] = hv;
      ((u64*)Alo)[g] = lv;
    }
  } else {
    __shared__ float tile[32][33];
    const int wb = blockIdx.x - NA_BLK;          // 0..2047
    const int n0 = (wb & 63) * 32, k0 = (wb >> 6) * 32;
    const int tx = threadIdx.x & 31, ty = threadIdx.x >> 5;  // ty 0..7
    #pragma unroll
    for (int r = 0; r < 4; ++r)
      tile[ty + r * 8][tx] = W1[(size_t)(k0 + ty + r * 8) * H_DIM + n0 + tx];
    __syncthreads();
    #pragma unroll
    for (int r = 0; r < 4; ++r) {
      const int n = n0 + ty + r * 8, k = k0 + tx;
      u16 h, l;
      split1(tile[tx][ty + r * 8], h, l);
      Bhi[(size_t)n * D_DIM + k] = h;
      Blo[(size_t)n * D_DIM + k] = l;
    }
  }
}

// ---------------- K2: bf16x3 MFMA fused scorer (r2-proven core + XCD swizzle) ----------------
// 1-D grid of 512. Linear block b -> xcd = b&7 (measured round-robin mapping);
// y (H half) = xcd&1 so each XCD touches ONE B half (4 MB hi+lo, L2-resident);
// x m-tile = (b>>3)*4 + (xcd>>1) (bijection onto 0..255).
// 256 threads = 4 waves in 2x2; wave tile 64x64; 16x16x32 bf16 MFMA.
// LDS tiles [row][BK=32] with XOR chunk swizzle slot = kc ^ ((row>>1)&3).

__device__ __forceinline__ void stage16(const u16* g, u16* l) {
  __builtin_amdgcn_global_load_lds((const GLOBAL_AS u32*)g, (LDS_AS u32*)l, 16, 0, 0);
}

__global__ __launch_bounds__(256, 2) void scorer_mfma(
    const u16* __restrict__ Ahi, const u16* __restrict__ Alo,
    const u16* __restrict__ Bhi, const u16* __restrict__ Blo,
    const float* __restrict__ b1, const float* __restrict__ W2,
    float* __restrict__ pl) {
  __shared__ u16 smem[4 * 128 * 32];  // 32 KB: Ahi | Alo | Bhi | Blo tiles
  u16* sAhi = smem;
  u16* sAlo = smem + 4096;
  u16* sBhi = smem + 8192;
  u16* sBlo = smem + 12288;

  const int tid = threadIdx.x;
  const int w = tid >> 6;   // wave 0..3
  const int l = tid & 63;

  const int b = blockIdx.x;
  const int xcd = b & 7;
  const int nyb = xcd & 1;                       // H half for this XCD
  const int m0 = ((b >> 3) * 4 + (xcd >> 1)) * 128;

  const int rl0 = w * 32 + (l >> 2);
  const int rl1 = rl0 + 16;
  const int kloc0 = (((l & 3) ^ ((rl0 >> 1) & 3)) << 3);
  const int kloc1 = (((l & 3) ^ ((rl1 >> 1) & 3)) << 3);
  const int lb0 = (w * 32) * 32;
  const int lb1 = (w * 32 + 16) * 32;

  int a_off[4], b_off[4];
  #pragma unroll
  for (int i = 0; i < 4; ++i) {
    int row = ((w & 1) << 6) + i * 16 + (l & 15);
    int slot = (l >> 4) ^ ((row >> 1) & 3);
    a_off[i] = row * 32 + slot * 8;
    int nrow = ((w >> 1) << 6) + i * 16 + (l & 15);
    int nslot = (l >> 4) ^ ((nrow >> 1) & 3);
    b_off[i] = nrow * 32 + nslot * 8;
  }

  float logit[4][4];
  #pragma unroll
  for (int i = 0; i < 4; ++i)
    #pragma unroll
    for (int r = 0; r < 4; ++r) logit[i][r] = 0.f;

  for (int t8 = 0; t8 < H_DIM / (128 * NSPLIT); ++t8) {
    const int n0 = nyb * (H_DIM / NSPLIT) + t8 * 128;
    f32x4 acc[4][4];
    #pragma unroll
    for (int i = 0; i < 4; ++i)
      #pragma unroll
      for (int j = 0; j < 4; ++j) acc[i][j] = (f32x4){0.f, 0.f, 0.f, 0.f};

    const u16* pA0h = Ahi + (size_t)(m0 + rl0) * D_DIM + kloc0;
    const u16* pA1h = Ahi + (size_t)(m0 + rl1) * D_DIM + kloc1;
    const u16* pA0l = Alo + (size_t)(m0 + rl0) * D_DIM + kloc0;
    const u16* pA1l = Alo + (size_t)(m0 + rl1) * D_DIM + kloc1;
    const u16* pB0h = Bhi + (size_t)(n0 + rl0) * D_DIM + kloc0;
    const u16* pB1h = Bhi + (size_t)(n0 + rl1) * D_DIM + kloc1;
    const u16* pB0l = Blo + (size_t)(n0 + rl0) * D_DIM + kloc0;
    const u16* pB1l = Blo + (size_t)(n0 + rl1) * D_DIM + kloc1;

    for (int k0 = 0; k0 < D_DIM; k0 += 32) {
      __syncthreads();
      stage16(pA0h, sAhi + lb0); stage16(pA1h, sAhi + lb1);
      stage16(pA0l, sAlo + lb0); stage16(pA1l, sAlo + lb1);
      stage16(pB0h, sBhi + lb0); stage16(pB1h, sBhi + lb1);
      stage16(pB0l, sBlo + lb0); stage16(pB1l, sBlo + lb1);
      pA0h += 32; pA1h += 32; pA0l += 32; pA1l += 32;
      pB0h += 32; pB1h += 32; pB0l += 32; pB1l += 32;
      __syncthreads();

      short8 ah[4], al[4], bh[4], bl[4];
      #pragma unroll
      for (int i = 0; i < 4; ++i) {
        ah[i] = *(const short8*)(sAhi + a_off[i]);
        al[i] = *(const short8*)(sAlo + a_off[i]);
        bh[i] = *(const short8*)(sBhi + b_off[i]);
        bl[i] = *(const short8*)(sBlo + b_off[i]);
      }
      #pragma unroll
      for (int i = 0; i < 4; ++i)
        #pragma unroll
        for (int j = 0; j < 4; ++j) {
          acc[i][j] = __builtin_amdgcn_mfma_f32_16x16x32_bf16(ah[i], bh[j], acc[i][j], 0, 0, 0);
          acc[i][j] = __builtin_amdgcn_mfma_f32_16x16x32_bf16(ah[i], bl[j], acc[i][j], 0, 0, 0);
          acc[i][j] = __builtin_amdgcn_mfma_f32_16x16x32_bf16(al[i], bh[j], acc[i][j], 0, 0, 0);
        }
    }

    const int nb = n0 + ((w >> 1) << 6);
    #pragma unroll
    for (int j = 0; j < 4; ++j) {
      const int n = nb + j * 16 + (l & 15);
      const float b1v = b1[n];
      const float w2v = W2[n];
      #pragma unroll
      for (int i = 0; i < 4; ++i)
        #pragma unroll
        for (int r = 0; r < 4; ++r)
          logit[i][r] += fmaxf(acc[i][j][r] + b1v, 0.f) * w2v;
    }
  }

  __syncthreads();
  float* red = (float*)smem;
  const int col = (l & 15) + ((w >> 1) << 4);
  #pragma unroll
  for (int i = 0; i < 4; ++i)
    #pragma unroll
    for (int r = 0; r < 4; ++r) {
      const int m = ((w & 1) << 6) + i * 16 + ((l >> 4) << 2) + r;
      red[m * 33 + col] = logit[i][r];
    }
  __syncthreads();
  if (tid < 128) {
    float s = 0.f;
    #pragma unroll
    for (int x = 0; x < 32; ++x) s += red[tid * 33 + x];
    pl[(size_t)nyb * M_TOK + m0 + tid] = s;
  }
}

// ---------------- fallback fp32 scorer (used only if ws too small) ----------------

__global__ __launch_bounds__(256) void scorer_kernel(
    const float* __restrict__ emb, const float* __restrict__ W1,
    const float* __restrict__ b1, const float* __restrict__ W2,
    const float* __restrict__ b2, float* __restrict__ pert) {
  __shared__ float As[16][68];
  __shared__ float Bs[16][132];
  __shared__ float red[64][17];

  const int tid = threadIdx.x;
  const int tx = tid & 15;
  const int ty = tid >> 4;
  const int m0 = blockIdx.x * 64;
  const int at = tid >> 2;
  const int ac = (tid & 3) << 2;
  const int br = tid >> 4;
  const int bc = (tid & 15) << 3;

  float logit[4] = {0.f, 0.f, 0.f, 0.f};

  for (int n0 = 0; n0 < H_DIM; n0 += 128) {
    float acc[4][8];
    #pragma unroll
    for (int i = 0; i < 4; i++)
      #pragma unroll
      for (int j = 0; j < 8; j++) acc[i][j] = 0.f;

    for (int k0 = 0; k0 < D_DIM; k0 += 16) {
      float4 av  = *(const float4*)(emb + (size_t)(m0 + at) * D_DIM + (k0 + ac));
      float4 bv0 = *(const float4*)(W1 + (size_t)(k0 + br) * H_DIM + (n0 + bc));
      float4 bv1 = *(const float4*)(W1 + (size_t)(k0 + br) * H_DIM + (n0 + bc) + 4);
      __syncthreads();
      As[ac + 0][at] = av.x; As[ac + 1][at] = av.y;
      As[ac + 2][at] = av.z; As[ac + 3][at] = av.w;
      *(float4*)&Bs[br][bc]     = bv0;
      *(float4*)&Bs[br][bc + 4] = bv1;
      __syncthreads();
      #pragma unroll
      for (int k = 0; k < 16; k++) {
        float4 a   = *(const float4*)&As[k][ty << 2];
        float4 b0  = *(const float4*)&Bs[k][tx << 3];
        float4 b1v = *(const float4*)&Bs[k][(tx << 3) + 4];
        float aa[4] = {a.x, a.y, a.z, a.w};
        float bb[8] = {b0.x, b0.y, b0.z, b0.w, b1v.x, b1v.y, b1v.z, b1v.w};
        #pragma unroll
        for (int i = 0; i < 4; i++)
          #pragma unroll
          for (int j = 0; j < 8; j++)
            acc[i][j] = fmaf(aa[i], bb[j], acc[i][j]);
      }
    }
    float4 c0 = *(const float4*)(b1 + n0 + (tx << 3));
    float4 c1 = *(const float4*)(b1 + n0 + (tx << 3) + 4);
    float4 w0 = *(const float4*)(W2 + n0 + (tx << 3));
    float4 w1 = *(const float4*)(W2 + n0 + (tx << 3) + 4);
    float cb[8] = {c0.x, c0.y, c0.z, c0.w, c1.x, c1.y, c1.z, c1.w};
    float wb[8] = {w0.x, w0.y, w0.z, w0.w, w1.x, w1.y, w1.z, w1.w};
    #pragma unroll
    for (int i = 0; i < 4; i++)
      #pragma unroll
      for (int j = 0; j < 8; j++) {
        float h = fmaxf(acc[i][j] + cb[j], 0.f);
        logit[i] = fmaf(h, wb[j], logit[i]);
      }
  }

  __syncthreads();
  #pragma unroll
  for (int i = 0; i < 4; i++) red[(ty << 2) + i][tx] = logit[i];
  __syncthreads();

  if (tid < 64) {
    float s = 0.f;
    #pragma unroll
    for (int x = 0; x < 16; x++) s += red[tid][x];
    s += b2[0];
    int t = m0 + tid;
    u32 r1a, r1b, r2a, r2b;
    jax_subkeys(r1a, r1b, r2a, r2b);
    pert[t] = s + gumbel_from_bits(jax_bits32(r2a, r2b, (u32)t));
  }
}

// ---------------- K3: binary-search top-k threshold -> hard mask ----------------
// Keys are UNIQUE 44-bit ints: (ordf(value)<<12) | token_idx. The k-th largest
// key T* = max{x : count(key >= x) >= k}; mask = (key >= T*). 44 uniform
// iterations, 1 barrier each, keys in 16 VGPR u64s per thread.

template <bool FROM_PL>
__device__ __forceinline__ void topk_body(const float* kl, const float* pl,
                                          const float* b2, float* mask,
                                          float* expk) {
  const int r = blockIdx.x;
  const int tid = threadIdx.x;
  const int w = tid >> 6, l = tid & 63;
  __shared__ int ksel_sh;
  __shared__ int cnt[2][4];

  u32 r1a, r1b, r2a, r2b;
  jax_subkeys(r1a, r1b, r2a, r2b);

  if (tid < 64) {
    float p = kl[l] + gumbel_from_bits(jax_bits32(r1a, r1b, (u32)l));
    u64 kkey = ((u64)ordf(p) << 32) | (unsigned)(63 - l);
    #pragma unroll
    for (int off = 32; off >= 1; off >>= 1) {
      u64 o = shflx64(kkey, off);
      if (o > kkey) kkey = o;
    }
    if (l == 0) ksel_sh = 64 - (int)(kkey & 0xffffffffu);
    if (r == 0) {
      float m = p;
      #pragma unroll
      for (int off = 32; off >= 1; off >>= 1) m = fmaxf(m, __shfl_xor(m, off));
      float e = expf(p - m);
      float s = e;
      #pragma unroll
      for (int off = 32; off >= 1; off >>= 1) s += __shfl_xor(s, off);
      float v = (e / s) * (float)(l + 1);
      #pragma unroll
      for (int off = 32; off >= 1; off >>= 1) v += __shfl_xor(v, off);
      if (l == 0) expk[0] = v;
    }
  }
  __syncthreads();
  const int k = ksel_sh;
  const float b2v = FROM_PL ? b2[0] : 0.f;

  u64 keys[16];
  #pragma unroll
  for (int j = 0; j < 16; j++) {
    int s = tid + (j << 8);
    int t = (r << 12) + s;
    float v;
    if (FROM_PL) {
      float acc = pl[t];
      #pragma unroll
      for (int q = 1; q < NSPLIT; ++q) acc += pl[(size_t)q * M_TOK + t];
      v = acc + b2v + gumbel_from_bits(jax_bits32(r2a, r2b, (u32)t));
    } else {
      v = mask[t];
    }
    keys[j] = ((u64)ordf(v) << 12) | (unsigned)s;
  }

  u64 lo = 0ull, hi = (1ull << 44) - 1ull;
  int it = 0;
  while (lo < hi) {
    const u64 mid = (lo + hi + 1ull) >> 1;
    int c = 0;
    #pragma unroll
    for (int j = 0; j < 16; j++) c += (keys[j] >= mid) ? 1 : 0;
    #pragma unroll
    for (int off = 32; off >= 1; off >>= 1) c += __shfl_xor(c, off);
    const int buf = it & 1;
    if (l == 0) cnt[buf][w] = c;
    __syncthreads();
    const int tot = cnt[buf][0] + cnt[buf][1] + cnt[buf][2] + cnt[buf][3];
    if (tot >= k) lo = mid; else hi = mid - 1ull;
    ++it;
  }
  const u64 thresh = lo;

  #pragma unroll
  for (int j = 0; j < 16; j++) {
    int s = tid + (j << 8);
    mask[(r << 12) + s] = (keys[j] >= thresh) ? 1.0f : 0.0f;
  }
}

__global__ __launch_bounds__(256) void topk_pl_kernel(const float* __restrict__ kl,
                                                      const float* __restrict__ pl,
                                                      const float* __restrict__ b2,
                                                      float* __restrict__ mask,
                                                      float* __restrict__ expk) {
  topk_body<true>(kl, pl, b2, mask, expk);
}

__global__ __launch_bounds__(256) void topk_kernel(const float* __restrict__ kl,
                                                   float* __restrict__ mask,
                                                   float* __restrict__ expk) {
  topk_body<false>(kl, nullptr, nullptr, mask, expk);
}

// ---------------- K4: filtered = emb * mask (grid-stride fat blocks) ----------------

__global__ __launch_bounds__(256) void filter_kernel(const float* __restrict__ emb,
                                                     const float* __restrict__ mask,
                                                     float* __restrict__ out) {
  const size_t total = (size_t)M_TOK * D_DIM / 4;
  for (size_t g = (size_t)blockIdx.x * 256 + threadIdx.x; g < total;
       g += (size_t)gridDim.x * 256) {
    const float mk = mask[g >> 8];           // 256 float4 = 1 token
    float4 v = ((const float4*)emb)[g];
    ((float4*)out)[g] = make_float4(v.x * mk, v.y * mk, v.z * mk, v.w * mk);
  }
}

// ---------------- launcher ----------------

extern "C" void kernel_launch(void* const* d_in, const int* in_sizes, int n_in,
                              void* d_out, int out_size, void* d_ws, size_t ws_size,
                              hipStream_t stream) {
  const float* emb = (const float*)d_in[0];
  const float* W1  = (const float*)d_in[1];
  const float* b1  = (const float*)d_in[2];
  const float* W2  = (const float*)d_in[3];
  const float* b2  = (const float*)d_in[4];
  const float* kl  = (const float*)d_in[5];
  float* out  = (float*)d_out;
  float* mask = out + (size_t)M_TOK * D_DIM;
  float* expk = mask + M_TOK;

  const size_t ws_need = (size_t)H_DIM * D_DIM * 2 * 2 + (size_t)NSPLIT * M_TOK * 4;

  if (ws_size >= ws_need) {
    u16* Ahi = (u16*)d_out;                      // A split reuses output region
    u16* Alo = Ahi + (size_t)M_TOK * D_DIM;
    u16* Bhi = (u16*)d_ws;
    u16* Blo = Bhi + (size_t)H_DIM * D_DIM;
    float* pl = (float*)(Blo + (size_t)H_DIM * D_DIM);

    split_fuse<<<NA_BLK + 2048, 256, 0, stream>>>(emb, Ahi, Alo, W1, Bhi, Blo);
    scorer_mfma<<<M_TOK / 128 * NSPLIT, 256, 0, stream>>>(Ahi, Alo, Bhi, Blo, b1, W2, pl);
    topk_pl_kernel<<<B_BATCH, 256, 0, stream>>>(kl, pl, b2, mask, expk);
  } else {
    scorer_kernel<<<M_TOK / 64, 256, 0, stream>>>(emb, W1, b1, W2, b2, mask);
    topk_kernel<<<B_BATCH, 256, 0, stream>>>(kl, mask, expk);
  }

  filter_kernel<<<2048, 256, 0, stream>>>(emb, mask, out);
}

// Round 7
// 700.042 us; speedup vs baseline: 1.0174x; 1.0174x over previous
//
#include <hip/hip_runtime.h>
#include <stdint.h>

#define B_BATCH 8
#define S_SEQ   4096
#define D_DIM   1024
#define H_DIM   2048
#define M_TOK   (B_BATCH * S_SEQ)   // 32768
#define MAXK    64
#define NSPLIT  2                   // H halves; one half per XCD parity

typedef unsigned int u32;
typedef unsigned short u16;
typedef unsigned long long u64;
typedef __attribute__((ext_vector_type(8))) short short8;   // 8 bf16 (4 VGPRs)
typedef __attribute__((ext_vector_type(4))) float f32x4;

#define GLOBAL_AS __attribute__((address_space(1)))
#define LDS_AS    __attribute__((address_space(3)))

// ---------------- JAX threefry2x32 (20 rounds), partitionable mode ----------------

#define TF_ROUND(x0, x1, r) { x0 += x1; x1 = ((x1 << r) | (x1 >> (32 - r))); x1 ^= x0; }

__device__ __forceinline__ void tf2x32(u32 k0, u32 k1, u32 x0, u32 x1, u32& o0, u32& o1) {
  u32 k2 = k0 ^ k1 ^ 0x1BD11BDAu;
  x0 += k0; x1 += k1;
  TF_ROUND(x0, x1, 13) TF_ROUND(x0, x1, 15) TF_ROUND(x0, x1, 26) TF_ROUND(x0, x1, 6)
  x0 += k1; x1 += k2 + 1u;
  TF_ROUND(x0, x1, 17) TF_ROUND(x0, x1, 29) TF_ROUND(x0, x1, 16) TF_ROUND(x0, x1, 24)
  x0 += k2; x1 += k0 + 2u;
  TF_ROUND(x0, x1, 13) TF_ROUND(x0, x1, 15) TF_ROUND(x0, x1, 26) TF_ROUND(x0, x1, 6)
  x0 += k0; x1 += k1 + 3u;
  TF_ROUND(x0, x1, 17) TF_ROUND(x0, x1, 29) TF_ROUND(x0, x1, 16) TF_ROUND(x0, x1, 24)
  x0 += k1; x1 += k2 + 4u;
  TF_ROUND(x0, x1, 13) TF_ROUND(x0, x1, 15) TF_ROUND(x0, x1, 26) TF_ROUND(x0, x1, 6)
  x0 += k2; x1 += k0 + 5u;
  o0 = x0; o1 = x1;
}

__device__ __forceinline__ void jax_subkeys(u32& r1a, u32& r1b, u32& r2a, u32& r2b) {
  tf2x32(0u, 42u, 0u, 0u, r1a, r1b);
  tf2x32(0u, 42u, 0u, 1u, r2a, r2b);
}

__device__ __forceinline__ u32 jax_bits32(u32 ka, u32 kb, u32 i) {
  u32 o0, o1;
  tf2x32(ka, kb, 0u, i, o0, o1);
  return o0 ^ o1;
}

__device__ __forceinline__ float jax_uniform_from_bits(u32 bits) {
  float f = __uint_as_float((bits >> 9) | 0x3f800000u) - 1.0f;
  float r = f + 1e-8f;
  return fmaxf(1e-8f, r);
}

__device__ __forceinline__ float gumbel_from_bits(u32 bits) {
  float u = jax_uniform_from_bits(bits);
  return -logf(-logf(u));
}

__device__ __forceinline__ u32 ordf(float v) {
  u32 b = __float_as_uint(v);
  return (b & 0x80000000u) ? ~b : (b | 0x80000000u);
}

__device__ __forceinline__ u64 shflx64(u64 v, int m) {
  unsigned lo = (unsigned)v, hi = (unsigned)(v >> 32);
  lo = (unsigned)__shfl_xor((int)lo, m);
  hi = (unsigned)__shfl_xor((int)hi, m);
  return ((u64)hi << 32) | lo;
}

// ---------------- bf16 split helpers ----------------

__device__ __forceinline__ u16 f2bf_rn(float x) {
  u32 u = __float_as_uint(x);
  u32 r = u + 0x7fffu + ((u >> 16) & 1u);
  return (u16)(r >> 16);
}

__device__ __forceinline__ void split1(float x, u16& h, u16& lo) {
  h = f2bf_rn(x);
  float hf = __uint_as_float(((u32)h) << 16);
  lo = f2bf_rn(x - hf);
}

// ---------------- split pre-passes (r5-proven forms) ----------------

__global__ __launch_bounds__(256) void split_a_kernel(const float* __restrict__ x,
                                                      u16* __restrict__ hi,
                                                      u16* __restrict__ lo) {
  const size_t i = ((size_t)blockIdx.x * 256 + threadIdx.x) * 4;
  float4 v = *(const float4*)(x + i);
  u16 h0, h1, h2, h3, l0, l1, l2, l3;
  split1(v.x, h0, l0); split1(v.y, h1, l1); split1(v.z, h2, l2); split1(v.w, h3, l3);
  u64 hv = (u64)h0 | ((u64)h1 << 16) | ((u64)h2 << 32) | ((u64)h3 << 48);
  u64 lv = (u64)l0 | ((u64)l1 << 16) | ((u64)l2 << 32) | ((u64)l3 << 48);
  *(u64*)(hi + i) = hv;
  *(u64*)(lo + i) = lv;
}

// transpose W1 [D][H] -> W1t [H][D], split to hi/lo bf16
__global__ __launch_bounds__(256) void split_w1t_kernel(const float* __restrict__ W1,
                                                        u16* __restrict__ bhi,
                                                        u16* __restrict__ blo) {
  __shared__ float tile[32][33];
  const int tx = threadIdx.x & 31, ty = threadIdx.x >> 5;  // ty 0..7
  const int n0 = blockIdx.x * 32, k0 = blockIdx.y * 32;
  #pragma unroll
  for (int r = 0; r < 4; ++r)
    tile[ty + r * 8][tx] = W1[(size_t)(k0 + ty + r * 8) * H_DIM + n0 + tx];
  __syncthreads();
  #pragma unroll
  for (int r = 0; r < 4; ++r) {
    const int n = n0 + ty + r * 8, k = k0 + tx;
    u16 h, l;
    split1(tile[tx][ty + r * 8], h, l);
    bhi[(size_t)n * D_DIM + k] = h;
    blo[(size_t)n * D_DIM + k] = l;
  }
}

// ---------------- K2: bf16x3 MFMA fused scorer, BK=64 ----------------
// 1-D grid 512; b -> xcd = b&7, H half = xcd&1, m-tile = (b>>3)*4 + (xcd>>1).
// 256 threads = 4 waves in 2x2; wave tile 64x64; 16x16x32 bf16 MFMA.
// BK=64: two 32-k sub-tiles staged per barrier pair -> 128 drains instead of 256.
// LDS 64 KB (grid already caps occupancy at 2 blocks/CU, so no occupancy loss).
// Each sub-tile: [row][32] with XOR chunk swizzle slot = kc ^ ((row>>1)&3).

__device__ __forceinline__ void stage16(const u16* g, u16* l) {
  __builtin_amdgcn_global_load_lds((const GLOBAL_AS u32*)g, (LDS_AS u32*)l, 16, 0, 0);
}

__global__ __launch_bounds__(256, 2) void scorer_mfma(
    const u16* __restrict__ Ahi, const u16* __restrict__ Alo,
    const u16* __restrict__ Bhi, const u16* __restrict__ Blo,
    const float* __restrict__ b1, const float* __restrict__ W2,
    float* __restrict__ pl) {
  __shared__ u16 smem[8 * 128 * 32];  // 64 KB: {Ahi,Alo,Bhi,Blo} x two 32-k sub-tiles
  u16* sAhi = smem;                   // each region: 2 sub-tiles x 4096 elems
  u16* sAlo = smem + 8192;
  u16* sBhi = smem + 16384;
  u16* sBlo = smem + 24576;

  const int tid = threadIdx.x;
  const int w = tid >> 6;   // wave 0..3
  const int l = tid & 63;

  const int b = blockIdx.x;
  const int xcd = b & 7;
  const int nyb = xcd & 1;                       // H half for this XCD
  const int m0 = ((b >> 3) * 4 + (xcd >> 1)) * 128;

  const int rl0 = w * 32 + (l >> 2);
  const int rl1 = rl0 + 16;
  const int kloc0 = (((l & 3) ^ ((rl0 >> 1) & 3)) << 3);
  const int kloc1 = (((l & 3) ^ ((rl1 >> 1) & 3)) << 3);
  const int lb0 = (w * 32) * 32;                 // elem offset within a sub-tile
  const int lb1 = (w * 32 + 16) * 32;

  int a_off[4], b_off[4];
  #pragma unroll
  for (int i = 0; i < 4; ++i) {
    int row = ((w & 1) << 6) + i * 16 + (l & 15);
    int slot = (l >> 4) ^ ((row >> 1) & 3);
    a_off[i] = row * 32 + slot * 8;
    int nrow = ((w >> 1) << 6) + i * 16 + (l & 15);
    int nslot = (l >> 4) ^ ((nrow >> 1) & 3);
    b_off[i] = nrow * 32 + nslot * 8;
  }

  float logit[4][4];
  #pragma unroll
  for (int i = 0; i < 4; ++i)
    #pragma unroll
    for (int r = 0; r < 4; ++r) logit[i][r] = 0.f;

  for (int t8 = 0; t8 < H_DIM / (128 * NSPLIT); ++t8) {
    const int n0 = nyb * (H_DIM / NSPLIT) + t8 * 128;
    f32x4 acc[4][4];
    #pragma unroll
    for (int i = 0; i < 4; ++i)
      #pragma unroll
      for (int j = 0; j < 4; ++j) acc[i][j] = (f32x4){0.f, 0.f, 0.f, 0.f};

    const u16* pA0h = Ahi + (size_t)(m0 + rl0) * D_DIM + kloc0;
    const u16* pA1h = Ahi + (size_t)(m0 + rl1) * D_DIM + kloc1;
    const u16* pA0l = Alo + (size_t)(m0 + rl0) * D_DIM + kloc0;
    const u16* pA1l = Alo + (size_t)(m0 + rl1) * D_DIM + kloc1;
    const u16* pB0h = Bhi + (size_t)(n0 + rl0) * D_DIM + kloc0;
    const u16* pB1h = Bhi + (size_t)(n0 + rl1) * D_DIM + kloc1;
    const u16* pB0l = Blo + (size_t)(n0 + rl0) * D_DIM + kloc0;
    const u16* pB1l = Blo + (size_t)(n0 + rl1) * D_DIM + kloc1;

    for (int k0 = 0; k0 < D_DIM; k0 += 64) {
      __syncthreads();   // previous BK tile fully consumed
      #pragma unroll
      for (int s = 0; s < 2; ++s) {
        const int so = s * 4096;     // sub-tile LDS offset (elems)
        const int sk = s * 32;       // sub-tile k offset (elems)
        stage16(pA0h + sk, sAhi + so + lb0); stage16(pA1h + sk, sAhi + so + lb1);
        stage16(pA0l + sk, sAlo + so + lb0); stage16(pA1l + sk, sAlo + so + lb1);
        stage16(pB0h + sk, sBhi + so + lb0); stage16(pB1h + sk, sBhi + so + lb1);
        stage16(pB0l + sk, sBlo + so + lb0); stage16(pB1l + sk, sBlo + so + lb1);
      }
      pA0h += 64; pA1h += 64; pA0l += 64; pA1l += 64;
      pB0h += 64; pB1h += 64; pB0l += 64; pB1l += 64;
      __syncthreads();   // loads landed (vmcnt drained before barrier)

      #pragma unroll
      for (int s = 0; s < 2; ++s) {
        const int so = s * 4096;
        short8 ah[4], al[4], bh[4], bl[4];
        #pragma unroll
        for (int i = 0; i < 4; ++i) {
          ah[i] = *(const short8*)(sAhi + so + a_off[i]);
          al[i] = *(const short8*)(sAlo + so + a_off[i]);
          bh[i] = *(const short8*)(sBhi + so + b_off[i]);
          bl[i] = *(const short8*)(sBlo + so + b_off[i]);
        }
        #pragma unroll
        for (int i = 0; i < 4; ++i)
          #pragma unroll
          for (int j = 0; j < 4; ++j) {
            acc[i][j] = __builtin_amdgcn_mfma_f32_16x16x32_bf16(ah[i], bh[j], acc[i][j], 0, 0, 0);
            acc[i][j] = __builtin_amdgcn_mfma_f32_16x16x32_bf16(ah[i], bl[j], acc[i][j], 0, 0, 0);
            acc[i][j] = __builtin_amdgcn_mfma_f32_16x16x32_bf16(al[i], bh[j], acc[i][j], 0, 0, 0);
          }
      }
    }

    const int nb = n0 + ((w >> 1) << 6);
    #pragma unroll
    for (int j = 0; j < 4; ++j) {
      const int n = nb + j * 16 + (l & 15);
      const float b1v = b1[n];
      const float w2v = W2[n];
      #pragma unroll
      for (int i = 0; i < 4; ++i)
        #pragma unroll
        for (int r = 0; r < 4; ++r)
          logit[i][r] += fmaxf(acc[i][j][r] + b1v, 0.f) * w2v;
    }
  }

  __syncthreads();
  float* red = (float*)smem;
  const int col = (l & 15) + ((w >> 1) << 4);
  #pragma unroll
  for (int i = 0; i < 4; ++i)
    #pragma unroll
    for (int r = 0; r < 4; ++r) {
      const int m = ((w & 1) << 6) + i * 16 + ((l >> 4) << 2) + r;
      red[m * 33 + col] = logit[i][r];
    }
  __syncthreads();
  if (tid < 128) {
    float s = 0.f;
    #pragma unroll
    for (int x = 0; x < 32; ++x) s += red[tid * 33 + x];
    pl[(size_t)nyb * M_TOK + m0 + tid] = s;
  }
}

// ---------------- fallback fp32 scorer (used only if ws too small) ----------------

__global__ __launch_bounds__(256) void scorer_kernel(
    const float* __restrict__ emb, const float* __restrict__ W1,
    const float* __restrict__ b1, const float* __restrict__ W2,
    const float* __restrict__ b2, float* __restrict__ pert) {
  __shared__ float As[16][68];
  __shared__ float Bs[16][132];
  __shared__ float red[64][17];

  const int tid = threadIdx.x;
  const int tx = tid & 15;
  const int ty = tid >> 4;
  const int m0 = blockIdx.x * 64;
  const int at = tid >> 2;
  const int ac = (tid & 3) << 2;
  const int br = tid >> 4;
  const int bc = (tid & 15) << 3;

  float logit[4] = {0.f, 0.f, 0.f, 0.f};

  for (int n0 = 0; n0 < H_DIM; n0 += 128) {
    float acc[4][8];
    #pragma unroll
    for (int i = 0; i < 4; i++)
      #pragma unroll
      for (int j = 0; j < 8; j++) acc[i][j] = 0.f;

    for (int k0 = 0; k0 < D_DIM; k0 += 16) {
      float4 av  = *(const float4*)(emb + (size_t)(m0 + at) * D_DIM + (k0 + ac));
      float4 bv0 = *(const float4*)(W1 + (size_t)(k0 + br) * H_DIM + (n0 + bc));
      float4 bv1 = *(const float4*)(W1 + (size_t)(k0 + br) * H_DIM + (n0 + bc) + 4);
      __syncthreads();
      As[ac + 0][at] = av.x; As[ac + 1][at] = av.y;
      As[ac + 2][at] = av.z; As[ac + 3][at] = av.w;
      *(float4*)&Bs[br][bc]     = bv0;
      *(float4*)&Bs[br][bc + 4] = bv1;
      __syncthreads();
      #pragma unroll
      for (int k = 0; k < 16; k++) {
        float4 a   = *(const float4*)&As[k][ty << 2];
        float4 b0  = *(const float4*)&Bs[k][tx << 3];
        float4 b1v = *(const float4*)&Bs[k][(tx << 3) + 4];
        float aa[4] = {a.x, a.y, a.z, a.w};
        float bb[8] = {b0.x, b0.y, b0.z, b0.w, b1v.x, b1v.y, b1v.z, b1v.w};
        #pragma unroll
        for (int i = 0; i < 4; i++)
          #pragma unroll
          for (int j = 0; j < 8; j++)
            acc[i][j] = fmaf(aa[i], bb[j], acc[i][j]);
      }
    }
    float4 c0 = *(const float4*)(b1 + n0 + (tx << 3));
    float4 c1 = *(const float4*)(b1 + n0 + (tx << 3) + 4);
    float4 w0 = *(const float4*)(W2 + n0 + (tx << 3));
    float4 w1 = *(const float4*)(W2 + n0 + (tx << 3) + 4);
    float cb[8] = {c0.x, c0.y, c0.z, c0.w, c1.x, c1.y, c1.z, c1.w};
    float wb[8] = {w0.x, w0.y, w0.z, w0.w, w1.x, w1.y, w1.z, w1.w};
    #pragma unroll
    for (int i = 0; i < 4; i++)
      #pragma unroll
      for (int j = 0; j < 8; j++) {
        float h = fmaxf(acc[i][j] + cb[j], 0.f);
        logit[i] = fmaf(h, wb[j], logit[i]);
      }
  }

  __syncthreads();
  #pragma unroll
  for (int i = 0; i < 4; i++) red[(ty << 2) + i][tx] = logit[i];
  __syncthreads();

  if (tid < 64) {
    float s = 0.f;
    #pragma unroll
    for (int x = 0; x < 16; x++) s += red[tid][x];
    s += b2[0];
    int t = m0 + tid;
    u32 r1a, r1b, r2a, r2b;
    jax_subkeys(r1a, r1b, r2a, r2b);
    pert[t] = s + gumbel_from_bits(jax_bits32(r2a, r2b, (u32)t));
  }
}

// ---------------- K3: binary-search top-k threshold -> hard mask ----------------
// Keys are UNIQUE 44-bit ints: (ordf(value)<<12) | token_idx. The k-th largest
// key T* = max{x : count(key >= x) >= k}; mask = (key >= T*). 44 uniform
// iterations, 1 barrier each, keys in 16 VGPR u64s per thread.

template <bool FROM_PL>
__device__ __forceinline__ void topk_body(const float* kl, const float* pl,
                                          const float* b2, float* mask,
                                          float* expk) {
  const int r = blockIdx.x;
  const int tid = threadIdx.x;
  const int w = tid >> 6, l = tid & 63;
  __shared__ int ksel_sh;
  __shared__ int cnt[2][4];

  u32 r1a, r1b, r2a, r2b;
  jax_subkeys(r1a, r1b, r2a, r2b);

  if (tid < 64) {
    float p = kl[l] + gumbel_from_bits(jax_bits32(r1a, r1b, (u32)l));
    u64 kkey = ((u64)ordf(p) << 32) | (unsigned)(63 - l);
    #pragma unroll
    for (int off = 32; off >= 1; off >>= 1) {
      u64 o = shflx64(kkey, off);
      if (o > kkey) kkey = o;
    }
    if (l == 0) ksel_sh = 64 - (int)(kkey & 0xffffffffu);
    if (r == 0) {
      float m = p;
      #pragma unroll
      for (int off = 32; off >= 1; off >>= 1) m = fmaxf(m, __shfl_xor(m, off));
      float e = expf(p - m);
      float s = e;
      #pragma unroll
      for (int off = 32; off >= 1; off >>= 1) s += __shfl_xor(s, off);
      float v = (e / s) * (float)(l + 1);
      #pragma unroll
      for (int off = 32; off >= 1; off >>= 1) v += __shfl_xor(v, off);
      if (l == 0) expk[0] = v;
    }
  }
  __syncthreads();
  const int k = ksel_sh;
  const float b2v = FROM_PL ? b2[0] : 0.f;

  u64 keys[16];
  #pragma unroll
  for (int j = 0; j < 16; j++) {
    int s = tid + (j << 8);
    int t = (r << 12) + s;
    float v;
    if (FROM_PL) {
      float acc = pl[t];
      #pragma unroll
      for (int q = 1; q < NSPLIT; ++q) acc += pl[(size_t)q * M_TOK + t];
      v = acc + b2v + gumbel_from_bits(jax_bits32(r2a, r2b, (u32)t));
    } else {
      v = mask[t];
    }
    keys[j] = ((u64)ordf(v) << 12) | (unsigned)s;
  }

  u64 lo = 0ull, hi = (1ull << 44) - 1ull;
  int it = 0;
  while (lo < hi) {
    const u64 mid = (lo + hi + 1ull) >> 1;
    int c = 0;
    #pragma unroll
    for (int j = 0; j < 16; j++) c += (keys[j] >= mid) ? 1 : 0;
    #pragma unroll
    for (int off = 32; off >= 1; off >>= 1) c += __shfl_xor(c, off);
    const int buf = it & 1;
    if (l == 0) cnt[buf][w] = c;
    __syncthreads();
    const int tot = cnt[buf][0] + cnt[buf][1] + cnt[buf][2] + cnt[buf][3];
    if (tot >= k) lo = mid; else hi = mid - 1ull;
    ++it;
  }
  const u64 thresh = lo;

  #pragma unroll
  for (int j = 0; j < 16; j++) {
    int s = tid + (j << 8);
    mask[(r << 12) + s] = (keys[j] >= thresh) ? 1.0f : 0.0f;
  }
}

__global__ __launch_bounds__(256) void topk_pl_kernel(const float* __restrict__ kl,
                                                      const float* __restrict__ pl,
                                                      const float* __restrict__ b2,
                                                      float* __restrict__ mask,
                                                      float* __restrict__ expk) {
  topk_body<true>(kl, pl, b2, mask, expk);
}

__global__ __launch_bounds__(256) void topk_kernel(const float* __restrict__ kl,
                                                   float* __restrict__ mask,
                                                   float* __restrict__ expk) {
  topk_body<false>(kl, nullptr, nullptr, mask, expk);
}

// ---------------- K4: filtered = emb * mask (r5-proven one-token blocks) ----------------

__global__ __launch_bounds__(256) void filter_kernel(const float* __restrict__ emb,
                                                     const float* __restrict__ mask,
                                                     float* __restrict__ out) {
  const int t = blockIdx.x;
  const float mk = mask[t];
  const size_t base = (size_t)t * D_DIM + ((size_t)threadIdx.x << 2);
  float4 v = *(const float4*)(emb + base);
  *(float4*)(out + base) = make_float4(v.x * mk, v.y * mk, v.z * mk, v.w * mk);
}

// ---------------- launcher ----------------

extern "C" void kernel_launch(void* const* d_in, const int* in_sizes, int n_in,
                              void* d_out, int out_size, void* d_ws, size_t ws_size,
                              hipStream_t stream) {
  const float* emb = (const float*)d_in[0];
  const float* W1  = (const float*)d_in[1];
  const float* b1  = (const float*)d_in[2];
  const float* W2  = (const float*)d_in[3];
  const float* b2  = (const float*)d_in[4];
  const float* kl  = (const float*)d_in[5];
  float* out  = (float*)d_out;
  float* mask = out + (size_t)M_TOK * D_DIM;
  float* expk = mask + M_TOK;

  const size_t ws_need = (size_t)H_DIM * D_DIM * 2 * 2 + (size_t)NSPLIT * M_TOK * 4;

  if (ws_size >= ws_need) {
    u16* Ahi = (u16*)d_out;                      // A split reuses output region
    u16* Alo = Ahi + (size_t)M_TOK * D_DIM;
    u16* Bhi = (u16*)d_ws;
    u16* Blo = Bhi + (size_t)H_DIM * D_DIM;
    float* pl = (float*)(Blo + (size_t)H_DIM * D_DIM);

    split_a_kernel<<<M_TOK * D_DIM / 1024, 256, 0, stream>>>(emb, Ahi, Alo);
    split_w1t_kernel<<<dim3(H_DIM / 32, D_DIM / 32), 256, 0, stream>>>(W1, Bhi, Blo);
    scorer_mfma<<<M_TOK / 128 * NSPLIT, 256, 0, stream>>>(Ahi, Alo, Bhi, Blo, b1, W2, pl);
    topk_pl_kernel<<<B_BATCH, 256, 0, stream>>>(kl, pl, b2, mask, expk);
  } else {
    scorer_kernel<<<M_TOK / 64, 256, 0, stream>>>(emb, W1, b1, W2, b2, mask);
    topk_kernel<<<B_BATCH, 256, 0, stream>>>(kl, mask, expk);
  }

  filter_kernel<<<M_TOK, 256, 0, stream>>>(emb, mask, out);
}